// Round 2
// baseline (563.837 us; speedup 1.0000x reference)
//
#include <hip/hip_runtime.h>
#include <hip/hip_cooperative_groups.h>

namespace cg = cooperative_groups;

#define BATCH 131072
#define SN 32
#define H1 10
#define H2 6
#define ROWS 128                           // rows per block; lane pairs (lane, lane+64)
#define GRID (BATCH / ROWS)                // 1024 blocks = exactly 4/CU on 256 CUs
#define TPB 512                            // 8 waves/block -> 32 waves/CU at 4 blocks/CU

// Fused kernel: 16 KB LDS exactly (4 blocks x 16 KB = 64 KB passes the
// cooperative residency check's 64K pool model; stride-33 pad was 16.9 KB
// and got the launch REJECTED -> zero output last round).
// XOR swizzle replaces the pad: element (r,c) at r*32 + (c ^ (r&31)).
//   column read/write (fixed c, r=lane / lane+64): banks c^0..c^31 -> 2-way, free
//   staged row writes (4 scalars):                2-way, free
#define SWZ(r, c) (((r) << 5) + ((c) ^ ((r) & 31)))

typedef float v2f __attribute__((ext_vector_type(2)));

__device__ __forceinline__ v2f bc(float s) { v2f r; r.x = s; r.y = s; return r; }
__device__ __forceinline__ v2f fma2(v2f a, v2f b, v2f c) {
    return __builtin_elementwise_fma(a, b, c);   // -> v_pk_fma_f32
}
__device__ __forceinline__ v2f tanh2(v2f x) {
    // tanh(x) = 1 - 2/(exp(2x)+1); exp/rcp scalar per component, rest packed
    v2f x2 = x + x;
    v2f e; e.x = __expf(x2.x); e.y = __expf(x2.y);
    v2f e1 = e + bc(1.0f);
    v2f r; r.x = __builtin_amdgcn_rcpf(e1.x); r.y = __builtin_amdgcn_rcpf(e1.y);
    return fma2(bc(-2.0f), r, bc(1.0f));
}

// DPP wave64 sum; total lands in lane 63. VALU-pipe only.
__device__ __forceinline__ float wave_sum(float v) {
    v += __int_as_float(__builtin_amdgcn_update_dpp(
            0, __float_as_int(v), 0x111, 0xf, 0xf, false));   // row_shr:1
    v += __int_as_float(__builtin_amdgcn_update_dpp(
            0, __float_as_int(v), 0x112, 0xf, 0xf, false));   // row_shr:2
    v += __int_as_float(__builtin_amdgcn_update_dpp(
            0, __float_as_int(v), 0x114, 0xf, 0xf, false));   // row_shr:4
    v += __int_as_float(__builtin_amdgcn_update_dpp(
            0, __float_as_int(v), 0x118, 0xf, 0xf, false));   // row_shr:8
    v += __int_as_float(__builtin_amdgcn_update_dpp(
            0, __float_as_int(v), 0x142, 0xa, 0xf, false));   // row_bcast:15
    v += __int_as_float(__builtin_amdgcn_update_dpp(
            0, __float_as_int(v), 0x143, 0xc, 0xf, false));   // row_bcast:31
    return v;
}

// ---------------- fused cooperative kernel ----------------
// phase 1: subnet eval; raw outputs overwrite xt in place; partials -> global
// grid.sync -> phase 2: blocks 0..95, wave 0: reduce partial row -> acc (double)
// grid.sync -> phase 3: per-wave stats from acc, normalize xt IN LDS,
//                       block 0/wave 0 computes loss, coalesced float4 store.
// Raw outputs never touch HBM (saves 16.8 MB W + 16.8 MB R + 2 launch gaps).
__global__ __launch_bounds__(TPB, 8) void k_fused(
    const float* __restrict__ x,
    const float* __restrict__ W1, const float* __restrict__ B1,
    const float* __restrict__ W2, const float* __restrict__ B2,
    const float* __restrict__ W3, const float* __restrict__ B3,
    float* __restrict__ out, float* __restrict__ partial /* [3*SN][GRID] */,
    double* __restrict__ acc /* [3*SN] */)
{
    __shared__ float xt[ROWS * 32];           // 16384 B exactly
    const int tid = threadIdx.x;
    const int lane = tid & 63;
    const int wave = tid >> 6;
    const int blk = blockIdx.x;

    // stage 128x32 x-tile coalesced, swizzle into LDS (2 float4/thread)
    const float4* xv = (const float4*)(x + (size_t)blk * ROWS * SN);
    #pragma unroll
    for (int it = 0; it < 2; ++it) {
        int v = it * TPB + tid;
        float4 val = xv[v];
        int r = v >> 3;                       // 8 float4 per row
        int c = (v & 7) << 2;
        xt[SWZ(r, c + 0)] = val.x;
        xt[SWZ(r, c + 1)] = val.y;
        xt[SWZ(r, c + 2)] = val.z;
        xt[SWZ(r, c + 3)] = val.w;
    }
    __syncthreads();

    // prefetch all 4 xs pairs: reads of columns {si*8+wave} all precede the
    // in-place overwrites (wave w only ever writes its own columns)
    v2f xs4[4];
    #pragma unroll
    for (int si = 0; si < 4; ++si) {
        int sc = si * 8 + wave;
        xs4[si].x = xt[SWZ(lane, sc)];
        xs4[si].y = xt[SWZ(lane + 64, sc)];
    }

    #pragma unroll 1
    for (int si = 0; si < 4; ++si) {
        // wave-uniform subnet id -> params land in SGPRs via s_load
        const int s = __builtin_amdgcn_readfirstlane(si * 8 + wave);
        const float* w1p = W1 + s * H1;
        const float* b1p = B1 + s * H1;
        const float* w2p = W2 + s * H1 * H2;
        const float* b2p = B2 + s * H2;
        const float* w3p = W3 + s * H2;
        const float b3 = B3[s];

        float w1r[H1], b1r[H1];
        #pragma unroll
        for (int i = 0; i < H1; ++i) { w1r[i] = w1p[i]; b1r[i] = b1p[i]; }
        float w2r[H1 * H2];
        #pragma unroll
        for (int k = 0; k < H1 * H2; ++k) w2r[k] = w2p[k];
        float b2r[H2], w3r[H2];
        #pragma unroll
        for (int j = 0; j < H2; ++j) { b2r[j] = b2p[j]; w3r[j] = w3p[j]; }

        v2f xs = xs4[si];

        // layer 1: t = tanh(x w1 + b1); p = (1-t^2) w1; q' = t (1-t^2) w1^2
        v2f t[H1], p[H1], q[H1];
        #pragma unroll
        for (int i = 0; i < H1; ++i) {
            v2f u = fma2(xs, bc(w1r[i]), bc(b1r[i]));
            v2f ti = tanh2(u);
            v2f e = fma2(-ti, ti, bc(1.0f));
            t[i] = ti;
            p[i] = e * bc(w1r[i]);
            q[i] = (ti * p[i]) * bc(w1r[i]);
        }

        v2f o = bc(b3), g2a = bc(0.0f);
        #pragma unroll
        for (int j = 0; j < H2; ++j) {
            v2f vv = bc(b2r[j]), a = bc(0.0f), c = bc(0.0f);
            #pragma unroll
            for (int i = 0; i < H1; ++i) {
                v2f wb = bc(w2r[i * H2 + j]);
                vv = fma2(wb, t[i], vv);
                a  = fma2(wb, p[i], a);
                c  = fma2(wb, q[i], c);
            }
            v2f sj = tanh2(vv);
            v2f dj = fma2(-sj, sj, bc(1.0f));            // 1 - s^2
            v2f aa = a * a;
            v2f h  = fma2(sj, aa, c);                    // c' + s a^2
            v2f k  = dj * h;                             // g2_j = -2 k
            o   = fma2(bc(w3r[j]), sj, o);
            g2a = fma2(bc(w3r[j]), k, g2a);              // g2_true = -2 g2a
        }

        // raw outputs overwrite the already-consumed xt column (kept in LDS)
        xt[SWZ(lane, s)] = o.x;
        xt[SWZ(lane + 64, s)] = o.y;

        v2f s2v = o * o;
        v2f s3v = (g2a * g2a) * bc(4.0f);                // (-2 g2a)^2
        float s1 = wave_sum(o.x + o.y);
        float s2 = wave_sum(s2v.x + s2v.y);
        float s3 = wave_sum(s3v.x + s3v.y);
        if (lane == 63) {
            partial[(size_t)(0 * SN + s) * GRID + blk] = s1;
            partial[(size_t)(1 * SN + s) * GRID + blk] = s2;
            partial[(size_t)(2 * SN + s) * GRID + blk] = s3;
        }
    }

    cg::this_grid().sync();

    // ---- phase 2: blocks 0..95, wave 0 only: partial[row][0..1024) -> acc[row]
    if (blk < 3 * SN && wave == 0) {
        const float4* pp4 = (const float4*)(partial + (size_t)blk * GRID);
        double sd = 0.0;
        #pragma unroll
        for (int k2 = 0; k2 < 4; ++k2) {                 // 4 coalesced float4 loads
            float4 v4 = pp4[k2 * 64 + lane];
            sd += (double)v4.x + (double)v4.y + (double)v4.z + (double)v4.w;
        }
        #pragma unroll
        for (int off = 32; off > 0; off >>= 1) sd += __shfl_down(sd, off);
        if (lane == 0) acc[blk] = sd;
    }

    cg::this_grid().sync();

    // ---- phase 3: stats per wave (double), normalize in LDS
    const double invB = 1.0 / (double)BATCH;
    #pragma unroll 1
    for (int si = 0; si < 4; ++si) {
        const int s = __builtin_amdgcn_readfirstlane(si * 8 + wave);
        double mean = acc[s] * invB;
        double var = acc[SN + s] * invB - mean * mean;
        if (var < 0.0) var = 0.0;
        const float m = (float)mean;
        const float inv = (float)(1.0 / sqrt(var + 1e-10));
        const int i0 = SWZ(lane, s);
        const int i1 = SWZ(lane + 64, s);
        xt[i0] = (xt[i0] - m) * inv;
        xt[i1] = (xt[i1] - m) * inv;
    }
    if (blk == 0 && wave == 0) {
        double term = 0.0;
        if (lane < SN) {
            double mean = acc[lane] * invB;
            double var = acc[SN + lane] * invB - mean * mean;
            if (var < 0.0) var = 0.0;
            term = (acc[2 * SN + lane] * invB) / sqrt(var);   // no eps (matches ref)
        }
        #pragma unroll
        for (int off = 16; off > 0; off >>= 1) term += __shfl_down(term, off);
        if (lane == 0) out[(size_t)BATCH * SN] = (float)(0.001 * term);
    }
    __syncthreads();

    // coalesced normalized store (reads scattered by swizzle: 2-way, free)
    float4* po = (float4*)out;
    const size_t base = (size_t)blk * (ROWS * SN / 4);
    #pragma unroll
    for (int it = 0; it < 2; ++it) {
        int v = it * TPB + tid;
        int r = v >> 3;
        int c = (v & 7) << 2;
        float4 w;
        w.x = xt[SWZ(r, c + 0)];
        w.y = xt[SWZ(r, c + 1)];
        w.z = xt[SWZ(r, c + 2)];
        w.w = xt[SWZ(r, c + 3)];
        po[base + v] = w;
    }
}

// ---------------- fallback: verbatim round-0 three-kernel path ----------------
#define LDS_STRIDE 33

__global__ __launch_bounds__(TPB) void k_main(
    const float* __restrict__ x,
    const float* __restrict__ W1, const float* __restrict__ B1,
    const float* __restrict__ W2, const float* __restrict__ B2,
    const float* __restrict__ W3, const float* __restrict__ B3,
    float* __restrict__ out, float* __restrict__ partial)
{
    __shared__ float xt[ROWS * LDS_STRIDE];
    const int tid = threadIdx.x;
    const int lane = tid & 63;
    const int wave = tid >> 6;
    const int blk = blockIdx.x;

    const float4* xv = (const float4*)(x + (size_t)blk * ROWS * SN);
    #pragma unroll
    for (int it = 0; it < 2; ++it) {
        int v = it * TPB + tid;
        float4 val = xv[v];
        int r = v >> 3;
        int c = (v & 7) << 2;
        float* dst = &xt[r * LDS_STRIDE + c];
        dst[0] = val.x; dst[1] = val.y; dst[2] = val.z; dst[3] = val.w;
    }
    __syncthreads();

    #pragma unroll 1
    for (int si = 0; si < 4; ++si) {
        const int s = __builtin_amdgcn_readfirstlane(si * 8 + wave);
        const float* w1p = W1 + s * H1;
        const float* b1p = B1 + s * H1;
        const float* w2p = W2 + s * H1 * H2;
        const float* b2p = B2 + s * H2;
        const float* w3p = W3 + s * H2;
        const float b3 = B3[s];

        float w1r[H1], b1r[H1];
        #pragma unroll
        for (int i = 0; i < H1; ++i) { w1r[i] = w1p[i]; b1r[i] = b1p[i]; }
        float w2r[H1 * H2];
        #pragma unroll
        for (int k = 0; k < H1 * H2; ++k) w2r[k] = w2p[k];
        float b2r[H2], w3r[H2];
        #pragma unroll
        for (int j = 0; j < H2; ++j) { b2r[j] = b2p[j]; w3r[j] = w3p[j]; }

        v2f xs;
        xs.x = xt[lane * LDS_STRIDE + s];
        xs.y = xt[(lane + 64) * LDS_STRIDE + s];

        v2f t[H1], p[H1], q[H1];
        #pragma unroll
        for (int i = 0; i < H1; ++i) {
            v2f u = fma2(xs, bc(w1r[i]), bc(b1r[i]));
            v2f ti = tanh2(u);
            v2f e = fma2(-ti, ti, bc(1.0f));
            t[i] = ti;
            p[i] = e * bc(w1r[i]);
            q[i] = (ti * p[i]) * bc(w1r[i]);
        }

        v2f o = bc(b3), g2a = bc(0.0f);
        #pragma unroll
        for (int j = 0; j < H2; ++j) {
            v2f vv = bc(b2r[j]), a = bc(0.0f), c = bc(0.0f);
            #pragma unroll
            for (int i = 0; i < H1; ++i) {
                v2f wb = bc(w2r[i * H2 + j]);
                vv = fma2(wb, t[i], vv);
                a  = fma2(wb, p[i], a);
                c  = fma2(wb, q[i], c);
            }
            v2f sj = tanh2(vv);
            v2f dj = fma2(-sj, sj, bc(1.0f));
            v2f aa = a * a;
            v2f h  = fma2(sj, aa, c);
            v2f k  = dj * h;
            o   = fma2(bc(w3r[j]), sj, o);
            g2a = fma2(bc(w3r[j]), k, g2a);
        }

        xt[lane * LDS_STRIDE + s] = o.x;
        xt[(lane + 64) * LDS_STRIDE + s] = o.y;

        v2f s2v = o * o;
        v2f s3v = (g2a * g2a) * bc(4.0f);
        float s1 = wave_sum(o.x + o.y);
        float s2 = wave_sum(s2v.x + s2v.y);
        float s3 = wave_sum(s3v.x + s3v.y);
        if (lane == 63) {
            partial[(size_t)(0 * SN + s) * GRID + blk] = s1;
            partial[(size_t)(1 * SN + s) * GRID + blk] = s2;
            partial[(size_t)(2 * SN + s) * GRID + blk] = s3;
        }
    }
    __syncthreads();

    float4* po = (float4*)out;
    const size_t base = (size_t)blk * (ROWS * SN / 4);
    #pragma unroll
    for (int it = 0; it < 2; ++it) {
        int v = it * TPB + tid;
        int r = v >> 3;
        int c = (v & 7) << 2;
        const float* src = &xt[r * LDS_STRIDE + c];
        float4 w; w.x = src[0]; w.y = src[1]; w.z = src[2]; w.w = src[3];
        po[base + v] = w;
    }
}

__global__ __launch_bounds__(256) void k_reduce(const float* __restrict__ partial,
                                                double* __restrict__ acc)
{
    const float* p = partial + (size_t)blockIdx.x * GRID;
    double s = 0.0;
    for (int i = threadIdx.x; i < GRID; i += 256) s += (double)p[i];
    #pragma unroll
    for (int off = 32; off > 0; off >>= 1) s += __shfl_down(s, off);
    __shared__ double ws[4];
    if ((threadIdx.x & 63) == 0) ws[threadIdx.x >> 6] = s;
    __syncthreads();
    if (threadIdx.x == 0) acc[blockIdx.x] = ws[0] + ws[1] + ws[2] + ws[3];
}

__global__ __launch_bounds__(256) void k_norm(float* __restrict__ out,
                                              const double* __restrict__ acc)
{
    __shared__ float mean_s[SN], inv_s[SN];
    const int tid = threadIdx.x;
    if (tid < SN) {
        const double invB = 1.0 / (double)BATCH;
        double mean = acc[tid] * invB;
        double var = acc[SN + tid] * invB - mean * mean;
        if (var < 0.0) var = 0.0;
        mean_s[tid] = (float)mean;
        inv_s[tid] = (float)(1.0 / sqrt(var + 1e-10));
    }
    if (blockIdx.x == 0 && tid == 0) {
        const double invB = 1.0 / (double)BATCH;
        double sum = 0.0;
        for (int s = 0; s < SN; ++s) {
            double mean = acc[s] * invB;
            double var = acc[SN + s] * invB - mean * mean;
            if (var < 0.0) var = 0.0;
            sum += (acc[2 * SN + s] * invB) / sqrt(var);
        }
        out[(size_t)BATCH * SN] = (float)(0.001 * sum);
    }
    __syncthreads();
    const int v = blockIdx.x * 256 + tid;
    float4* p = (float4*)out;
    float4 val = p[v];
    const int c = (v & 7) << 2;
    val.x = (val.x - mean_s[c + 0]) * inv_s[c + 0];
    val.y = (val.y - mean_s[c + 1]) * inv_s[c + 1];
    val.z = (val.z - mean_s[c + 2]) * inv_s[c + 2];
    val.w = (val.w - mean_s[c + 3]) * inv_s[c + 3];
    p[v] = val;
}

extern "C" void kernel_launch(void* const* d_in, const int* in_sizes, int n_in,
                              void* d_out, int out_size, void* d_ws, size_t ws_size,
                              hipStream_t stream) {
    const float* x  = (const float*)d_in[0];
    const float* W1 = (const float*)d_in[1];
    const float* B1 = (const float*)d_in[2];
    const float* W2 = (const float*)d_in[3];
    const float* B2 = (const float*)d_in[4];
    const float* W3 = (const float*)d_in[5];
    const float* B3 = (const float*)d_in[6];

    float* out = (float*)d_out;                 // [BATCH*SN] out_bn, then [1] loss
    float* partial = (float*)d_ws;              // [3*SN][GRID] f32, fully overwritten
    double* acc = (double*)((char*)d_ws + (size_t)3 * SN * GRID * sizeof(float));

    void* args[10];
    args[0] = (void*)&x;  args[1] = (void*)&W1; args[2] = (void*)&B1;
    args[3] = (void*)&W2; args[4] = (void*)&B2; args[5] = (void*)&W3;
    args[6] = (void*)&B3; args[7] = (void*)&out; args[8] = (void*)&partial;
    args[9] = (void*)&acc;
    hipError_t err = hipLaunchCooperativeKernel((const void*)k_fused, dim3(GRID),
                                                dim3(TPB), args, 0, stream);
    if (err != hipSuccess) {
        // fallback: known-good three-kernel path (round-0 parity)
        k_main<<<GRID, TPB, 0, stream>>>(x, W1, B1, W2, B2, W3, B3, out, partial);
        k_reduce<<<3 * SN, 256, 0, stream>>>(partial, acc);
        k_norm<<<(BATCH * SN / 4) / 256, 256, 0, stream>>>(out, acc);
    }
}

// Round 3
// 368.646 us; speedup vs baseline: 1.5295x; 1.5295x over previous
//
#include <hip/hip_runtime.h>
#include <hip/hip_cooperative_groups.h>

namespace cg = cooperative_groups;

#define BATCH 131072
#define SN 32
#define H1 10
#define H2 6
#define ROWS 128                           // rows per block; lane pairs (lane, lane+64)
#define GRID (BATCH / ROWS)                // 1024 blocks = exactly 4/CU on 256 CUs
#define TPB 512                            // 8 waves/block -> 32 waves/CU at 4 blocks/CU

// 16 KB LDS exactly (4 x 16 KB = 64 KB passes the cooperative residency
// pool model; stride-33 pad at 16.9 KB got the launch rejected in R1).
// XOR swizzle: element (r,c) at r*32 + (c ^ (r&31)).
//   column read/write (fixed c, r = lane / lane+64): 2-way bank alias, free
//   staged row writes (4 scalars):                   2-way, free
#define SWZ(r, c) (((r) << 5) + ((c) ^ ((r) & 31)))

typedef float v2f __attribute__((ext_vector_type(2)));

__device__ __forceinline__ v2f bc(float s) { v2f r; r.x = s; r.y = s; return r; }
__device__ __forceinline__ v2f fma2(v2f a, v2f b, v2f c) {
    return __builtin_elementwise_fma(a, b, c);   // -> v_pk_fma_f32
}
__device__ __forceinline__ v2f tanh2(v2f x) {
    // tanh(x) = 1 - 2/(exp(2x)+1); exp/rcp scalar per component, rest packed
    v2f x2 = x + x;
    v2f e; e.x = __expf(x2.x); e.y = __expf(x2.y);
    v2f e1 = e + bc(1.0f);
    v2f r; r.x = __builtin_amdgcn_rcpf(e1.x); r.y = __builtin_amdgcn_rcpf(e1.y);
    return fma2(bc(-2.0f), r, bc(1.0f));
}

// DPP wave64 sum; total lands in lane 63. VALU-pipe only.
__device__ __forceinline__ float wave_sum(float v) {
    v += __int_as_float(__builtin_amdgcn_update_dpp(
            0, __float_as_int(v), 0x111, 0xf, 0xf, false));   // row_shr:1
    v += __int_as_float(__builtin_amdgcn_update_dpp(
            0, __float_as_int(v), 0x112, 0xf, 0xf, false));   // row_shr:2
    v += __int_as_float(__builtin_amdgcn_update_dpp(
            0, __float_as_int(v), 0x114, 0xf, 0xf, false));   // row_shr:4
    v += __int_as_float(__builtin_amdgcn_update_dpp(
            0, __float_as_int(v), 0x118, 0xf, 0xf, false));   // row_shr:8
    v += __int_as_float(__builtin_amdgcn_update_dpp(
            0, __float_as_int(v), 0x142, 0xa, 0xf, false));   // row_bcast:15
    v += __int_as_float(__builtin_amdgcn_update_dpp(
            0, __float_as_int(v), 0x143, 0xc, 0xf, false));   // row_bcast:31
    return v;
}

// ---------------- fused cooperative kernel ----------------
// phase 1: subnet eval; raw outputs overwrite xt in place; partials -> global
// grid.sync -> phase 2: blocks 0..95, wave 0: reduce partial row -> acc (double)
// grid.sync -> phase 3: per-wave stats from acc, normalize xt IN LDS,
//                       block 0/wave 0 computes loss, coalesced float4 store.
// R2 lesson: under the (512,8) VGPR cap the compiler spilled t/p/q[H1]
// (940 MB scratch traffic, 11x slowdown). This version hand-interchanges the
// i/j loops so the working set is structurally 18 v2f accumulators (~55 VGPR
// peak) -- no t/p/q arrays exist to spill.
__global__ __launch_bounds__(TPB, 8) void k_fused(
    const float* __restrict__ x,
    const float* __restrict__ W1, const float* __restrict__ B1,
    const float* __restrict__ W2, const float* __restrict__ B2,
    const float* __restrict__ W3, const float* __restrict__ B3,
    float* __restrict__ out, float* __restrict__ partial /* [3*SN][GRID] */,
    double* __restrict__ acc /* [3*SN] */)
{
    __shared__ float xt[ROWS * 32];           // 16384 B exactly
    const int tid = threadIdx.x;
    const int lane = tid & 63;
    const int wave = tid >> 6;
    const int blk = blockIdx.x;

    // stage 128x32 x-tile coalesced, swizzle into LDS (2 float4/thread)
    const float4* xv = (const float4*)(x + (size_t)blk * ROWS * SN);
    #pragma unroll
    for (int it = 0; it < 2; ++it) {
        int v = it * TPB + tid;
        float4 val = xv[v];
        int r = v >> 3;                       // 8 float4 per row
        int c = (v & 7) << 2;
        xt[SWZ(r, c + 0)] = val.x;
        xt[SWZ(r, c + 1)] = val.y;
        xt[SWZ(r, c + 2)] = val.z;
        xt[SWZ(r, c + 3)] = val.w;
    }
    __syncthreads();

    #pragma unroll 1
    for (int si = 0; si < 4; ++si) {
        // wave-uniform subnet id -> params land in SGPRs via s_load
        const int s = __builtin_amdgcn_readfirstlane(si * 8 + wave);
        const float* w1p = W1 + s * H1;
        const float* b1p = B1 + s * H1;
        const float* w2p = W2 + s * H1 * H2;
        const float* b2p = B2 + s * H2;
        const float* w3p = W3 + s * H2;
        const float b3 = B3[s];

        float w1r[H1], b1r[H1];
        #pragma unroll
        for (int i = 0; i < H1; ++i) { w1r[i] = w1p[i]; b1r[i] = b1p[i]; }
        float w2r[H1 * H2];
        #pragma unroll
        for (int k = 0; k < H1 * H2; ++k) w2r[k] = w2p[k];
        float b2r[H2], w3r[H2];
        #pragma unroll
        for (int j = 0; j < H2; ++j) { b2r[j] = b2p[j]; w3r[j] = w3p[j]; }

        // safe in-place read: this wave's column si*8+wave is read here and
        // only overwritten by this same wave at the end of this iteration
        v2f xs;
        xs.x = xt[SWZ(lane, s)];
        xs.y = xt[(size_t)SWZ(lane + 64, s)];

        // interchanged loops: accumulate layer-2 pre-activations and their
        // 1st/2nd-derivative companions directly (no t/p/q arrays).
        // vv_j = b2_j + sum_i w2_ij t_i ; av_j = sum_i w2_ij p_i ;
        // cv_j = sum_i w2_ij q'_i  with p_i=(1-t^2)w1, q'_i=t(1-t^2)w1^2
        v2f vv[H2], av[H2], cv[H2];
        #pragma unroll
        for (int j = 0; j < H2; ++j) {
            vv[j] = bc(b2r[j]); av[j] = bc(0.0f); cv[j] = bc(0.0f);
        }
        #pragma unroll
        for (int i = 0; i < H1; ++i) {
            v2f u  = fma2(xs, bc(w1r[i]), bc(b1r[i]));
            v2f ti = tanh2(u);
            v2f e  = fma2(-ti, ti, bc(1.0f));
            v2f pi = e * bc(w1r[i]);
            v2f qi = (ti * pi) * bc(w1r[i]);
            #pragma unroll
            for (int j = 0; j < H2; ++j) {
                v2f wb = bc(w2r[i * H2 + j]);
                vv[j] = fma2(wb, ti, vv[j]);
                av[j] = fma2(wb, pi, av[j]);
                cv[j] = fma2(wb, qi, cv[j]);
            }
        }

        v2f o = bc(b3), g2a = bc(0.0f);
        #pragma unroll
        for (int j = 0; j < H2; ++j) {
            v2f sj = tanh2(vv[j]);
            v2f dj = fma2(-sj, sj, bc(1.0f));            // 1 - s^2
            v2f aa = av[j] * av[j];
            v2f h  = fma2(sj, aa, cv[j]);                // c' + s a^2
            v2f kk = dj * h;                             // g2_j = -2 kk
            o   = fma2(bc(w3r[j]), sj, o);
            g2a = fma2(bc(w3r[j]), kk, g2a);             // g2_true = -2 g2a
        }

        // raw outputs overwrite the already-consumed xt column (kept in LDS)
        xt[SWZ(lane, s)] = o.x;
        xt[SWZ(lane + 64, s)] = o.y;

        v2f s2v = o * o;
        v2f s3v = (g2a * g2a) * bc(4.0f);                // (-2 g2a)^2
        float s1 = wave_sum(o.x + o.y);
        float s2 = wave_sum(s2v.x + s2v.y);
        float s3 = wave_sum(s3v.x + s3v.y);
        if (lane == 63) {
            partial[(size_t)(0 * SN + s) * GRID + blk] = s1;
            partial[(size_t)(1 * SN + s) * GRID + blk] = s2;
            partial[(size_t)(2 * SN + s) * GRID + blk] = s3;
        }
    }

    cg::this_grid().sync();

    // ---- phase 2: blocks 0..95, wave 0 only: partial[row][0..1024) -> acc[row]
    if (blk < 3 * SN && wave == 0) {
        const float4* pp4 = (const float4*)(partial + (size_t)blk * GRID);
        double sd = 0.0;
        #pragma unroll
        for (int k2 = 0; k2 < 4; ++k2) {                 // 4 coalesced float4 loads
            float4 v4 = pp4[k2 * 64 + lane];
            sd += (double)v4.x + (double)v4.y + (double)v4.z + (double)v4.w;
        }
        #pragma unroll
        for (int off = 32; off > 0; off >>= 1) sd += __shfl_down(sd, off);
        if (lane == 0) acc[blk] = sd;
    }

    cg::this_grid().sync();

    // ---- phase 3: stats per wave (double, matches ref), normalize in LDS
    const double invB = 1.0 / (double)BATCH;
    #pragma unroll 1
    for (int si = 0; si < 4; ++si) {
        const int s = __builtin_amdgcn_readfirstlane(si * 8 + wave);
        double mean = acc[s] * invB;
        double var = acc[SN + s] * invB - mean * mean;
        if (var < 0.0) var = 0.0;
        const float m = (float)mean;
        const float inv = (float)(1.0 / sqrt(var + 1e-10));
        const int i0 = SWZ(lane, s);
        const int i1 = SWZ(lane + 64, s);
        xt[i0] = (xt[i0] - m) * inv;
        xt[i1] = (xt[i1] - m) * inv;
    }
    if (blk == 0 && wave == 0) {
        double term = 0.0;
        if (lane < SN) {
            double mean = acc[lane] * invB;
            double var = acc[SN + lane] * invB - mean * mean;
            if (var < 0.0) var = 0.0;
            term = (acc[2 * SN + lane] * invB) / sqrt(var);   // no eps (matches ref)
        }
        #pragma unroll
        for (int off = 16; off > 0; off >>= 1) term += __shfl_down(term, off);
        if (lane == 0) out[(size_t)BATCH * SN] = (float)(0.001 * term);
    }
    __syncthreads();

    // coalesced normalized store (reads scattered by swizzle: 2-way, free)
    float4* po = (float4*)out;
    const size_t base = (size_t)blk * (ROWS * SN / 4);
    #pragma unroll
    for (int it = 0; it < 2; ++it) {
        int v = it * TPB + tid;
        int r = v >> 3;
        int c = (v & 7) << 2;
        float4 w;
        w.x = xt[SWZ(r, c + 0)];
        w.y = xt[SWZ(r, c + 1)];
        w.z = xt[SWZ(r, c + 2)];
        w.w = xt[SWZ(r, c + 3)];
        po[base + v] = w;
    }
}

// ---------------- fallback: verbatim round-0 three-kernel path ----------------
#define LDS_STRIDE 33

__global__ __launch_bounds__(TPB) void k_main(
    const float* __restrict__ x,
    const float* __restrict__ W1, const float* __restrict__ B1,
    const float* __restrict__ W2, const float* __restrict__ B2,
    const float* __restrict__ W3, const float* __restrict__ B3,
    float* __restrict__ out, float* __restrict__ partial)
{
    __shared__ float xt[ROWS * LDS_STRIDE];
    const int tid = threadIdx.x;
    const int lane = tid & 63;
    const int wave = tid >> 6;
    const int blk = blockIdx.x;

    const float4* xv = (const float4*)(x + (size_t)blk * ROWS * SN);
    #pragma unroll
    for (int it = 0; it < 2; ++it) {
        int v = it * TPB + tid;
        float4 val = xv[v];
        int r = v >> 3;
        int c = (v & 7) << 2;
        float* dst = &xt[r * LDS_STRIDE + c];
        dst[0] = val.x; dst[1] = val.y; dst[2] = val.z; dst[3] = val.w;
    }
    __syncthreads();

    #pragma unroll 1
    for (int si = 0; si < 4; ++si) {
        const int s = __builtin_amdgcn_readfirstlane(si * 8 + wave);
        const float* w1p = W1 + s * H1;
        const float* b1p = B1 + s * H1;
        const float* w2p = W2 + s * H1 * H2;
        const float* b2p = B2 + s * H2;
        const float* w3p = W3 + s * H2;
        const float b3 = B3[s];

        float w1r[H1], b1r[H1];
        #pragma unroll
        for (int i = 0; i < H1; ++i) { w1r[i] = w1p[i]; b1r[i] = b1p[i]; }
        float w2r[H1 * H2];
        #pragma unroll
        for (int k = 0; k < H1 * H2; ++k) w2r[k] = w2p[k];
        float b2r[H2], w3r[H2];
        #pragma unroll
        for (int j = 0; j < H2; ++j) { b2r[j] = b2p[j]; w3r[j] = w3p[j]; }

        v2f xs;
        xs.x = xt[lane * LDS_STRIDE + s];
        xs.y = xt[(lane + 64) * LDS_STRIDE + s];

        v2f t[H1], p[H1], q[H1];
        #pragma unroll
        for (int i = 0; i < H1; ++i) {
            v2f u = fma2(xs, bc(w1r[i]), bc(b1r[i]));
            v2f ti = tanh2(u);
            v2f e = fma2(-ti, ti, bc(1.0f));
            t[i] = ti;
            p[i] = e * bc(w1r[i]);
            q[i] = (ti * p[i]) * bc(w1r[i]);
        }

        v2f o = bc(b3), g2a = bc(0.0f);
        #pragma unroll
        for (int j = 0; j < H2; ++j) {
            v2f vv = bc(b2r[j]), a = bc(0.0f), c = bc(0.0f);
            #pragma unroll
            for (int i = 0; i < H1; ++i) {
                v2f wb = bc(w2r[i * H2 + j]);
                vv = fma2(wb, t[i], vv);
                a  = fma2(wb, p[i], a);
                c  = fma2(wb, q[i], c);
            }
            v2f sj = tanh2(vv);
            v2f dj = fma2(-sj, sj, bc(1.0f));
            v2f aa = a * a;
            v2f h  = fma2(sj, aa, c);
            v2f k  = dj * h;
            o   = fma2(bc(w3r[j]), sj, o);
            g2a = fma2(bc(w3r[j]), k, g2a);
        }

        xt[lane * LDS_STRIDE + s] = o.x;
        xt[(lane + 64) * LDS_STRIDE + s] = o.y;

        v2f s2v = o * o;
        v2f s3v = (g2a * g2a) * bc(4.0f);
        float s1 = wave_sum(o.x + o.y);
        float s2 = wave_sum(s2v.x + s2v.y);
        float s3 = wave_sum(s3v.x + s3v.y);
        if (lane == 63) {
            partial[(size_t)(0 * SN + s) * GRID + blk] = s1;
            partial[(size_t)(1 * SN + s) * GRID + blk] = s2;
            partial[(size_t)(2 * SN + s) * GRID + blk] = s3;
        }
    }
    __syncthreads();

    float4* po = (float4*)out;
    const size_t base = (size_t)blk * (ROWS * SN / 4);
    #pragma unroll
    for (int it = 0; it < 2; ++it) {
        int v = it * TPB + tid;
        int r = v >> 3;
        int c = (v & 7) << 2;
        const float* src = &xt[r * LDS_STRIDE + c];
        float4 w; w.x = src[0]; w.y = src[1]; w.z = src[2]; w.w = src[3];
        po[base + v] = w;
    }
}

__global__ __launch_bounds__(256) void k_reduce(const float* __restrict__ partial,
                                                double* __restrict__ acc)
{
    const float* p = partial + (size_t)blockIdx.x * GRID;
    double s = 0.0;
    for (int i = threadIdx.x; i < GRID; i += 256) s += (double)p[i];
    #pragma unroll
    for (int off = 32; off > 0; off >>= 1) s += __shfl_down(s, off);
    __shared__ double ws[4];
    if ((threadIdx.x & 63) == 0) ws[threadIdx.x >> 6] = s;
    __syncthreads();
    if (threadIdx.x == 0) acc[blockIdx.x] = ws[0] + ws[1] + ws[2] + ws[3];
}

__global__ __launch_bounds__(256) void k_norm(float* __restrict__ out,
                                              const double* __restrict__ acc)
{
    __shared__ float mean_s[SN], inv_s[SN];
    const int tid = threadIdx.x;
    if (tid < SN) {
        const double invB = 1.0 / (double)BATCH;
        double mean = acc[tid] * invB;
        double var = acc[SN + tid] * invB - mean * mean;
        if (var < 0.0) var = 0.0;
        mean_s[tid] = (float)mean;
        inv_s[tid] = (float)(1.0 / sqrt(var + 1e-10));
    }
    if (blockIdx.x == 0 && tid == 0) {
        const double invB = 1.0 / (double)BATCH;
        double sum = 0.0;
        for (int s = 0; s < SN; ++s) {
            double mean = acc[s] * invB;
            double var = acc[SN + s] * invB - mean * mean;
            if (var < 0.0) var = 0.0;
            sum += (acc[2 * SN + s] * invB) / sqrt(var);
        }
        out[(size_t)BATCH * SN] = (float)(0.001 * sum);
    }
    __syncthreads();
    const int v = blockIdx.x * 256 + tid;
    float4* p = (float4*)out;
    float4 val = p[v];
    const int c = (v & 7) << 2;
    val.x = (val.x - mean_s[c + 0]) * inv_s[c + 0];
    val.y = (val.y - mean_s[c + 1]) * inv_s[c + 1];
    val.z = (val.z - mean_s[c + 2]) * inv_s[c + 2];
    val.w = (val.w - mean_s[c + 3]) * inv_s[c + 3];
    p[v] = val;
}

extern "C" void kernel_launch(void* const* d_in, const int* in_sizes, int n_in,
                              void* d_out, int out_size, void* d_ws, size_t ws_size,
                              hipStream_t stream) {
    const float* x  = (const float*)d_in[0];
    const float* W1 = (const float*)d_in[1];
    const float* B1 = (const float*)d_in[2];
    const float* W2 = (const float*)d_in[3];
    const float* B2 = (const float*)d_in[4];
    const float* W3 = (const float*)d_in[5];
    const float* B3 = (const float*)d_in[6];

    float* out = (float*)d_out;                 // [BATCH*SN] out_bn, then [1] loss
    float* partial = (float*)d_ws;              // [3*SN][GRID] f32, fully overwritten
    double* acc = (double*)((char*)d_ws + (size_t)3 * SN * GRID * sizeof(float));

    void* args[10];
    args[0] = (void*)&x;  args[1] = (void*)&W1; args[2] = (void*)&B1;
    args[3] = (void*)&W2; args[4] = (void*)&B2; args[5] = (void*)&W3;
    args[6] = (void*)&B3; args[7] = (void*)&out; args[8] = (void*)&partial;
    args[9] = (void*)&acc;
    hipError_t err = hipLaunchCooperativeKernel((const void*)k_fused, dim3(GRID),
                                                dim3(TPB), args, 0, stream);
    if (err != hipSuccess) {
        // fallback: known-good three-kernel path (round-0 parity)
        k_main<<<GRID, TPB, 0, stream>>>(x, W1, B1, W2, B2, W3, B3, out, partial);
        k_reduce<<<3 * SN, 256, 0, stream>>>(partial, acc);
        k_norm<<<(BATCH * SN / 4) / 256, 256, 0, stream>>>(out, acc);
    }
}

// Round 8
// 132.233 us; speedup vs baseline: 4.2640x; 2.7879x over previous
//
#include <hip/hip_runtime.h>

#define BATCH 131072
#define SN 32
#define H1 10
#define H2 6
#define ROWS 128                           // rows per block; lane pairs (lane, lane+64)
#define GRID (BATCH / ROWS)                // 1024
#define TPB 512                            // 8 waves/block -> 32 waves/CU at 4 blocks/CU
#define LDS_STRIDE 33                      // bank = (row + s) % 32 -> 2-way (free)

#define FB 512                             // k_finish blocks
#define FT 256                             // k_finish threads

typedef float v2f __attribute__((ext_vector_type(2)));

__device__ __forceinline__ v2f bc(float s) { v2f r; r.x = s; r.y = s; return r; }
__device__ __forceinline__ v2f fma2(v2f a, v2f b, v2f c) {
    return __builtin_elementwise_fma(a, b, c);   // -> v_pk_fma_f32
}
__device__ __forceinline__ v2f tanh2(v2f x) {
    // tanh(x) = 1 - 2/(exp(2x)+1); exp/rcp scalar per component, rest packed
    v2f x2 = x + x;
    v2f e; e.x = __expf(x2.x); e.y = __expf(x2.y);
    v2f e1 = e + bc(1.0f);
    v2f r; r.x = __builtin_amdgcn_rcpf(e1.x); r.y = __builtin_amdgcn_rcpf(e1.y);
    return fma2(bc(-2.0f), r, bc(1.0f));
}

// DPP wave64 sum; total lands in lane 63. VALU-pipe only.
__device__ __forceinline__ float wave_sum(float v) {
    v += __int_as_float(__builtin_amdgcn_update_dpp(
            0, __float_as_int(v), 0x111, 0xf, 0xf, false));   // row_shr:1
    v += __int_as_float(__builtin_amdgcn_update_dpp(
            0, __float_as_int(v), 0x112, 0xf, 0xf, false));   // row_shr:2
    v += __int_as_float(__builtin_amdgcn_update_dpp(
            0, __float_as_int(v), 0x114, 0xf, 0xf, false));   // row_shr:4
    v += __int_as_float(__builtin_amdgcn_update_dpp(
            0, __float_as_int(v), 0x118, 0xf, 0xf, false));   // row_shr:8
    v += __int_as_float(__builtin_amdgcn_update_dpp(
            0, __float_as_int(v), 0x142, 0xa, 0xf, false));   // row_bcast:15
    v += __int_as_float(__builtin_amdgcn_update_dpp(
            0, __float_as_int(v), 0x143, 0xc, 0xf, false));   // row_bcast:31
    return v;
}

// ---------------- k_main: verbatim round-0 (proven 43.8 us, 44 VGPR) --------
// NO cooperative API anywhere in this file: R4-R7 produced 4 harness crashes
// with coop binaries (vs R2/R3 where coop ran) -- this submission is the
// clean experiment: if a pure non-coop binary also crashes, the infra is
// broken regardless of code; if it passes, we bank the k_reduce+k_norm merge.
__global__ __launch_bounds__(TPB) void k_main(
    const float* __restrict__ x,
    const float* __restrict__ W1, const float* __restrict__ B1,
    const float* __restrict__ W2, const float* __restrict__ B2,
    const float* __restrict__ W3, const float* __restrict__ B3,
    float* __restrict__ out, float* __restrict__ partial /* [3*SN][GRID] */)
{
    __shared__ float xt[ROWS * LDS_STRIDE];   // 16.9 KB (x tile, then raw outputs)
    const int tid = threadIdx.x;
    const int lane = tid & 63;
    const int wave = tid >> 6;                // 0..7
    const int blk = blockIdx.x;

    // stage 128x32 x-tile coalesced, transpose-pad into LDS (2 float4/thread)
    const float4* xv = (const float4*)(x + (size_t)blk * ROWS * SN);
    #pragma unroll
    for (int it = 0; it < 2; ++it) {
        int v = it * TPB + tid;
        float4 val = xv[v];
        int r = v >> 3;                       // 8 float4 per row
        int c = (v & 7) << 2;
        float* dst = &xt[r * LDS_STRIDE + c];
        dst[0] = val.x; dst[1] = val.y; dst[2] = val.z; dst[3] = val.w;
    }
    __syncthreads();

    #pragma unroll 1
    for (int si = 0; si < 4; ++si) {
        // wave-uniform subnet id -> params land in SGPRs via s_load
        const int s = __builtin_amdgcn_readfirstlane(si * 8 + wave);
        const float* w1p = W1 + s * H1;
        const float* b1p = B1 + s * H1;
        const float* w2p = W2 + s * H1 * H2;
        const float* b2p = B2 + s * H2;
        const float* w3p = W3 + s * H2;
        const float b3 = B3[s];

        float w1r[H1], b1r[H1];
        #pragma unroll
        for (int i = 0; i < H1; ++i) { w1r[i] = w1p[i]; b1r[i] = b1p[i]; }
        float w2r[H1 * H2];
        #pragma unroll
        for (int k = 0; k < H1 * H2; ++k) w2r[k] = w2p[k];
        float b2r[H2], w3r[H2];
        #pragma unroll
        for (int j = 0; j < H2; ++j) { b2r[j] = b2p[j]; w3r[j] = w3p[j]; }

        v2f xs;
        xs.x = xt[lane * LDS_STRIDE + s];
        xs.y = xt[(lane + 64) * LDS_STRIDE + s];

        // layer 1: t = tanh(x w1 + b1); p = (1-t^2) w1; q' = t (1-t^2) w1^2
        v2f t[H1], p[H1], q[H1];
        #pragma unroll
        for (int i = 0; i < H1; ++i) {
            v2f u = fma2(xs, bc(w1r[i]), bc(b1r[i]));
            v2f ti = tanh2(u);
            v2f e = fma2(-ti, ti, bc(1.0f));
            t[i] = ti;
            p[i] = e * bc(w1r[i]);
            q[i] = (ti * p[i]) * bc(w1r[i]);
        }

        v2f o = bc(b3), g2a = bc(0.0f);
        #pragma unroll
        for (int j = 0; j < H2; ++j) {
            v2f vv = bc(b2r[j]), a = bc(0.0f), c = bc(0.0f);
            #pragma unroll
            for (int i = 0; i < H1; ++i) {
                v2f wb = bc(w2r[i * H2 + j]);
                vv = fma2(wb, t[i], vv);
                a  = fma2(wb, p[i], a);
                c  = fma2(wb, q[i], c);
            }
            v2f sj = tanh2(vv);
            v2f dj = fma2(-sj, sj, bc(1.0f));            // 1 - s^2
            v2f aa = a * a;
            v2f h  = fma2(sj, aa, c);                    // c' + s a^2
            v2f k  = dj * h;                             // g2_j = -2 k
            o   = fma2(bc(w3r[j]), sj, o);
            g2a = fma2(bc(w3r[j]), k, g2a);              // g2_true = -2 g2a
        }

        // raw outputs overwrite the just-consumed xt column (same wave)
        xt[lane * LDS_STRIDE + s] = o.x;
        xt[(lane + 64) * LDS_STRIDE + s] = o.y;

        v2f s2v = o * o;
        v2f s3v = (g2a * g2a) * bc(4.0f);                // (-2 g2a)^2
        float s1 = wave_sum(o.x + o.y);
        float s2 = wave_sum(s2v.x + s2v.y);
        float s3 = wave_sum(s3v.x + s3v.y);
        if (lane == 63) {
            partial[(size_t)(0 * SN + s) * GRID + blk] = s1;
            partial[(size_t)(1 * SN + s) * GRID + blk] = s2;
            partial[(size_t)(2 * SN + s) * GRID + blk] = s3;
        }
    }
    __syncthreads();

    // coalesced raw-output store
    float4* po = (float4*)out;
    const size_t base = (size_t)blk * (ROWS * SN / 4);
    #pragma unroll
    for (int it = 0; it < 2; ++it) {
        int v = it * TPB + tid;
        int r = v >> 3;
        int c = (v & 7) << 2;
        const float* src = &xt[r * LDS_STRIDE + c];
        float4 w; w.x = src[0]; w.y = src[1]; w.z = src[2]; w.w = src[3];
        po[base + v] = w;
    }
}

// ---------------- k_finish: merged reduce + normalize (replaces k_reduce
// + k_norm; one dispatch + one graph gap saved). Each block REDUNDANTLY
// reduces partial[96][1024] (393 KB, L2-resident -> ~3 MB HBM total across
// 512 blocks), derives the 32 subnet stats in LDS (double, matches ref),
// then grid-strides the normalization of out. No cross-block dependency.
__global__ __launch_bounds__(FT) void k_finish(float* __restrict__ out,
                                               const float* __restrict__ partial)
{
    __shared__ double red_s[3 * SN];          // 96 row sums
    __shared__ float mean_s[SN], inv_s[SN];
    const int tid = threadIdx.x;
    const int lane = tid & 63;
    const int wave = tid >> 6;                // 0..3

    // waves reduce rows round-robin: row = 1024 floats = 4 float4/lane
    for (int r = wave; r < 3 * SN; r += 4) {
        const float4* pr = (const float4*)(partial + (size_t)r * GRID);
        double sd = 0.0;
        #pragma unroll
        for (int k = 0; k < 4; ++k) {
            float4 v4 = pr[k * 64 + lane];    // coalesced
            sd += (double)v4.x + (double)v4.y + (double)v4.z + (double)v4.w;
        }
        #pragma unroll
        for (int off = 32; off > 0; off >>= 1) sd += __shfl_down(sd, off);
        if (lane == 0) red_s[r] = sd;
    }
    __syncthreads();

    const double invB = 1.0 / (double)BATCH;
    if (tid < SN) {
        double mean = red_s[tid] * invB;
        double var = red_s[SN + tid] * invB - mean * mean;
        if (var < 0.0) var = 0.0;
        mean_s[tid] = (float)mean;
        inv_s[tid] = (float)(1.0 / sqrt(var + 1e-10));
    }
    if (blockIdx.x == 0 && tid == 0) {
        double sum = 0.0;
        for (int s = 0; s < SN; ++s) {
            double mean = red_s[s] * invB;
            double var = red_s[SN + s] * invB - mean * mean;
            if (var < 0.0) var = 0.0;
            sum += (red_s[2 * SN + s] * invB) / sqrt(var);   // no eps (matches ref)
        }
        out[(size_t)BATCH * SN] = (float)(0.001 * sum);
    }
    __syncthreads();

    // grid-stride normalize: 1,048,576 float4 over 512x256 threads = 8/thread
    float4* p = (float4*)out;
    const int total = BATCH * SN / 4;
    for (int v = blockIdx.x * FT + tid; v < total; v += FB * FT) {
        float4 val = p[v];
        const int c = (v & 7) << 2;                       // subnet base
        val.x = (val.x - mean_s[c + 0]) * inv_s[c + 0];
        val.y = (val.y - mean_s[c + 1]) * inv_s[c + 1];
        val.z = (val.z - mean_s[c + 2]) * inv_s[c + 2];
        val.w = (val.w - mean_s[c + 3]) * inv_s[c + 3];
        p[v] = val;
    }
}

extern "C" void kernel_launch(void* const* d_in, const int* in_sizes, int n_in,
                              void* d_out, int out_size, void* d_ws, size_t ws_size,
                              hipStream_t stream) {
    const float* x  = (const float*)d_in[0];
    const float* W1 = (const float*)d_in[1];
    const float* B1 = (const float*)d_in[2];
    const float* W2 = (const float*)d_in[3];
    const float* B2 = (const float*)d_in[4];
    const float* W3 = (const float*)d_in[5];
    const float* B3 = (const float*)d_in[6];

    float* out = (float*)d_out;                 // [BATCH*SN] out_bn, then [1] loss
    float* partial = (float*)d_ws;              // [3*SN][GRID] f32, fully overwritten

    k_main<<<GRID, TPB, 0, stream>>>(x, W1, B1, W2, B2, W3, B3, out, partial);
    k_finish<<<FB, FT, 0, stream>>>(out, partial);
}